// Round 8
// baseline (41.244 us; speedup 1.0000x reference)
//
#include <hip/hip_runtime.h>
#include <hip/hip_bf16.h>

// Problem constants (match reference)
#define NN 1024
#define FF 256
#define DD 64
#define RR 11
#define EE 2048
#define ALPHA 0.2f
#define NB 256
#define TPB 512
#define EPT (EE / TPB)      // 4 edges per thread in phase 1
#define PERM_CAP 2176       // >= 2048 + 11*7 padding
#define PQ_N (FF * RR)      // 2816

// ws layout (bytes):
//   0     : int cnt                  (memset to 0 each call)
//   256   : int ntiles
//   512   : int perm[PERM_CAP]       (8704 B)
//   12288 : float2 mxinv[FF]         (2 KB)    {m[f], 1/s[f]}
//   16384 : float2 pqT[FF*RR]        (22.5 KB) pqT[f*RR+r] = {p,q}
// Only ~33 KB of dirty state crosses the barrier (no cbuf!) -> the agent
// acquire/release pair is cheap (R4's 17 MB writeback storm is gone).

__global__ __launch_bounds__(TPB) void gat_one(
    const float* __restrict__ x, const float* __restrict__ W,
    const float* __restrict__ a, const int* __restrict__ src,
    const int* __restrict__ dst, const int* __restrict__ rel,
    float* __restrict__ out,
    int* __restrict__ cnt, int* __restrict__ ntiles_p,
    int* __restrict__ perm, float2* __restrict__ mxinv,
    float2* __restrict__ pqT) {

    const int b    = blockIdx.x;   // 0..255 == feature f
    const int tid  = threadIdx.x;  // 0..511
    const int wid  = tid >> 6;     // 0..7
    const int lane = tid & 63;

    __shared__ float  xcol[NN];       // 4 KB: x[:, f]
    __shared__ float  p_sh[RR], q_sh[RR];
    __shared__ float  red_m[8], red_s[8];
    __shared__ int    hist[16], off_sh[16];
    __shared__ int    nt_sh;
    __shared__ float2 pq_lds[PQ_N];   // 22.5 KB (phase 2)
    __shared__ float2 mx_lds[FF];     // 2 KB   (phase 2)

    // ================= Phase 1: per-feature stats =================
    const int f = b;
    // stage column f of x
    for (int i = tid; i < NN; i += TPB) xcol[i] = x[(size_t)i * FF + f];

    // own-feature p/q: p[r]=dot(W[r,f,:],a[:64]), q[r]=dot(W[r,f,:],a[64:])
    for (int r = wid; r < RR; r += 8) {
        float w  = W[((size_t)r * FF + f) * DD + lane];
        float pa = w * a[lane];
        float qa = w * a[DD + lane];
        #pragma unroll
        for (int o = 32; o > 0; o >>= 1) {
            pa += __shfl_down(pa, o);
            qa += __shfl_down(qa, o);
        }
        if (lane == 0) { p_sh[r] = pa; q_sh[r] = qa; }
    }
    __syncthreads();   // xcol + p_sh/q_sh ready
    if (tid < RR) pqT[f * RR + tid] = make_float2(p_sh[tid], q_sh[tid]);

    // scores for all edges (4/thread) from LDS; softmax stats over edge axis
    float vals[EPT];
    float m = -INFINITY;
    #pragma unroll
    for (int k = 0; k < EPT; ++k) {
        int e = tid + k * TPB;
        float xs = xcol[src[e]];
        float xd = xcol[dst[e]];
        int r = rel[e];
        float v = xs * p_sh[r] + xd * q_sh[r];
        v = v > 0.0f ? v : ALPHA * v;
        vals[k] = v;
        m = fmaxf(m, v);
    }
    #pragma unroll
    for (int o = 32; o > 0; o >>= 1) m = fmaxf(m, __shfl_down(m, o));
    if (lane == 0) red_m[wid] = m;
    __syncthreads();
    m = red_m[0];
    #pragma unroll
    for (int i = 1; i < 8; ++i) m = fmaxf(m, red_m[i]);

    float s = 0.0f;
    #pragma unroll
    for (int k = 0; k < EPT; ++k) s += expf(vals[k] - m);
    #pragma unroll
    for (int o = 32; o > 0; o >>= 1) s += __shfl_down(s, o);
    if (lane == 0) red_s[wid] = s;
    __syncthreads();
    float st = red_s[0];
    #pragma unroll
    for (int i = 1; i < 8; ++i) st += red_s[i];

    if (tid == 0) mxinv[f] = make_float2(m, 1.0f / st);

    // block 0: counting sort of edges by relation (buckets padded to 8)
    if (b == 0) {
        if (tid < 16) hist[tid] = 0;
        __syncthreads();
        for (int e = tid; e < EE; e += TPB) atomicAdd(&hist[rel[e]], 1);
        __syncthreads();
        if (tid == 0) {
            int acc = 0;
            for (int r = 0; r < RR; ++r) {
                off_sh[r] = acc;
                acc += (hist[r] + 7) & ~7;
            }
            *ntiles_p = acc >> 3;      // tiles of 8 edges
        }
        __syncthreads();
        for (int i = tid; i < PERM_CAP; i += TPB) perm[i] = -1;
        __syncthreads();
        for (int e = tid; e < EE; e += TPB) {
            int pos = atomicAdd(&off_sh[rel[e]], 1);
            perm[pos] = e;
        }
    }

    // ================= Grid barrier (R4-proven) =================
    // RELEASE arrival (flushes this block's dirty lines), RELAXED spin
    // (no cache maintenance per poll), one agent ACQUIRE fence on exit,
    // then plain loads of the published tables.
    __syncthreads();
    if (tid == 0) {
        __hip_atomic_fetch_add(cnt, 1, __ATOMIC_RELEASE,
                               __HIP_MEMORY_SCOPE_AGENT);
        while (__hip_atomic_load(cnt, __ATOMIC_RELAXED,
                                 __HIP_MEMORY_SCOPE_AGENT) < NB) {
            __builtin_amdgcn_s_sleep(2);
        }
        __builtin_amdgcn_fence(__ATOMIC_ACQUIRE, "agent");
        nt_sh = *ntiles_p;             // plain load, ordered after fence
    }
    __syncthreads();

    // stage tables into LDS (~25 KB per block, from L3/L2)
    for (int i = tid; i < PQ_N; i += TPB) pq_lds[i] = pqT[i];
    if (tid < FF) mx_lds[tid] = mxinv[tid];
    __syncthreads();

    // ================= Phase 2: relation-sorted output =================
    const int ntiles = nt_sh;
    const int fg = lane >> 4;        // 0..3: f within a 4-group
    const int dq = lane & 15;        // 0..15: d-quad
    for (int t = b; t < ntiles; t += NB) {
        int e = perm[t * 8 + wid];
        if (e < 0) continue;
        int r  = rel[e];
        int si = src[e], di = dst[e];
        const float* __restrict__ xrs = x + (size_t)si * FF;
        const float* __restrict__ xrd = x + (size_t)di * FF;
        const float* __restrict__ Wr  = W + (size_t)r * FF * DD;
        float4 acc = make_float4(0.f, 0.f, 0.f, 0.f);
        #pragma unroll 8
        for (int fb = 0; fb < FF; fb += 4) {
            int ff = fb + fg;
            float xs = xrs[ff];
            float xd = xrd[ff];
            float2 pqv = pq_lds[ff * RR + r];
            float2 mi  = mx_lds[ff];
            float v = xs * pqv.x + xd * pqv.y;
            v = v > 0.0f ? v : ALPHA * v;
            float c = expf(v - mi.x) * mi.y * xd;   // attn[e,f] * x[dst,f]
            float4 w4 = *(const float4*)&Wr[(size_t)ff * DD + dq * 4];
            acc.x = fmaf(c, w4.x, acc.x);
            acc.y = fmaf(c, w4.y, acc.y);
            acc.z = fmaf(c, w4.z, acc.z);
            acc.w = fmaf(c, w4.w, acc.w);
        }
        #pragma unroll
        for (int o = 16; o <= 32; o <<= 1) {
            acc.x += __shfl_xor(acc.x, o);
            acc.y += __shfl_xor(acc.y, o);
            acc.z += __shfl_xor(acc.z, o);
            acc.w += __shfl_xor(acc.w, o);
        }
        if (fg == 0)
            *(float4*)&out[(size_t)e * DD + dq * 4] = acc;
    }
}

extern "C" void kernel_launch(void* const* d_in, const int* in_sizes, int n_in,
                              void* d_out, int out_size, void* d_ws, size_t ws_size,
                              hipStream_t stream) {
    const float* x  = (const float*)d_in[0];   // [N, F]
    const float* W  = (const float*)d_in[1];   // [R, F, D]
    const float* a  = (const float*)d_in[2];   // [2*D]
    const int* src  = (const int*)d_in[3];     // [E]
    const int* dst  = (const int*)d_in[4];     // [E]
    const int* rel  = (const int*)d_in[5];     // [E]
    float* out      = (float*)d_out;           // [E*D]

    char* wsb = (char*)d_ws;
    int*    cnt      = (int*)wsb;
    int*    ntiles_p = (int*)(wsb + 256);
    int*    perm     = (int*)(wsb + 512);
    float2* mxinv    = (float2*)(wsb + 12288);
    float2* pqT      = (float2*)(wsb + 16384);

    hipMemsetAsync(cnt, 0, 64, stream);   // reset barrier each call (graph-safe)
    gat_one<<<NB, TPB, 0, stream>>>(x, W, a, src, dst, rel, out,
                                    cnt, ntiles_p, perm, mxinv, pqT);
}

// Round 9
// 23.426 us; speedup vs baseline: 1.7606x; 1.7606x over previous
//
#include <hip/hip_runtime.h>
#include <hip/hip_bf16.h>

// Problem constants (match reference)
#define NN 1024
#define FF 256
#define DD 64
#define RR 11
#define EE 2048
#define ALPHA 0.2f
#define TPB 512
#define EPT (EE / TPB)          // 4 edges per thread in K1
#define PERM_CAP 2176           // >= 2048 + 11*7 padding
#define K2_GRID (PERM_CAP / 8)  // 272 tiles max (ntiles <= 267)

// ws layout (bytes):
//   0     : int ntiles
//   256   : int perm[PERM_CAP]   (8704 B)
//   16384 : float cbuf[EE*FF]    (2 MB, e-major: cbuf[e*FF+f])
// Kernel boundary = device-wide sync (proven cheaper than any SW barrier).

// K1: block = feature f. Stage x[:,f] in LDS; own p/q; scores from LDS;
//     softmax over edge axis; write c[e,f]=attn*x[dst,f] (e-major).
//     Block 0 additionally counting-sorts edges by relation.
__global__ __launch_bounds__(TPB) void k1_coef(
    const float* __restrict__ x, const float* __restrict__ W,
    const float* __restrict__ a, const int* __restrict__ src,
    const int* __restrict__ dst, const int* __restrict__ rel,
    float* __restrict__ cbuf, int* __restrict__ perm,
    int* __restrict__ ntiles_p) {

    const int f    = blockIdx.x;   // 0..255
    const int tid  = threadIdx.x;  // 0..511
    const int wid  = tid >> 6;     // 0..7
    const int lane = tid & 63;

    __shared__ float xcol[NN];     // 4 KB: x[:, f]
    __shared__ float p_sh[RR], q_sh[RR];
    __shared__ float red_m[8], red_s[8];
    __shared__ int   hist[16], off_sh[16];

    // stage column f of x: 2 strided loads/thread (replaces 8 scattered/thread)
    for (int i = tid; i < NN; i += TPB) xcol[i] = x[(size_t)i * FF + f];

    // own-feature p/q: p[r]=dot(W[r,f,:],a[:64]), q[r]=dot(W[r,f,:],a[64:])
    for (int r = wid; r < RR; r += 8) {
        float w  = W[((size_t)r * FF + f) * DD + lane];
        float pa = w * a[lane];
        float qa = w * a[DD + lane];
        #pragma unroll
        for (int o = 32; o > 0; o >>= 1) {
            pa += __shfl_down(pa, o);
            qa += __shfl_down(qa, o);
        }
        if (lane == 0) { p_sh[r] = pa; q_sh[r] = qa; }
    }
    __syncthreads();   // xcol + p_sh/q_sh ready

    // scores for all edges (4/thread) from LDS; softmax over the edge axis
    float vals[EPT], xd_v[EPT];
    float m = -INFINITY;
    #pragma unroll
    for (int k = 0; k < EPT; ++k) {
        int e = tid + k * TPB;
        float xs = xcol[src[e]];
        float xd = xcol[dst[e]];
        int r = rel[e];
        float v = xs * p_sh[r] + xd * q_sh[r];
        v = v > 0.0f ? v : ALPHA * v;
        vals[k] = v;
        xd_v[k] = xd;
        m = fmaxf(m, v);
    }
    #pragma unroll
    for (int o = 32; o > 0; o >>= 1) m = fmaxf(m, __shfl_down(m, o));
    if (lane == 0) red_m[wid] = m;
    __syncthreads();
    m = red_m[0];
    #pragma unroll
    for (int i = 1; i < 8; ++i) m = fmaxf(m, red_m[i]);

    float s = 0.0f;
    #pragma unroll
    for (int k = 0; k < EPT; ++k) {
        vals[k] = expf(vals[k] - m);
        s += vals[k];
    }
    #pragma unroll
    for (int o = 32; o > 0; o >>= 1) s += __shfl_down(s, o);
    if (lane == 0) red_s[wid] = s;
    __syncthreads();
    float st = red_s[0];
    #pragma unroll
    for (int i = 1; i < 8; ++i) st += red_s[i];
    float inv = 1.0f / st;

    // fused coefficient c[e,f] = attn[e,f]*x[dst,f], e-major (lazy writeback)
    #pragma unroll
    for (int k = 0; k < EPT; ++k) {
        int e = tid + k * TPB;
        cbuf[(size_t)e * FF + f] = vals[k] * inv * xd_v[k];
    }

    // block 0: counting sort of edges by relation (buckets padded to 8)
    if (f == 0) {
        if (tid < 16) hist[tid] = 0;
        __syncthreads();
        for (int e = tid; e < EE; e += TPB) atomicAdd(&hist[rel[e]], 1);
        __syncthreads();
        if (tid == 0) {
            int acc = 0;
            for (int r = 0; r < RR; ++r) {
                off_sh[r] = acc;
                acc += (hist[r] + 7) & ~7;
            }
            *ntiles_p = acc >> 3;      // tiles of 8 edges
        }
        __syncthreads();
        for (int i = tid; i < PERM_CAP; i += TPB) perm[i] = -1;
        __syncthreads();
        for (int e = tid; e < EE; e += TPB) {
            int pos = atomicAdd(&off_sh[rel[e]], 1);
            perm[pos] = e;
        }
    }
}

// K2: block = tile of 8 same-relation edges (one wave per edge). W_r streamed
//     through LDS in 8KB chunks shared by all 8 waves (global W traffic 8x
//     lower than per-wave streaming). c read e-major contiguous.
__global__ __launch_bounds__(TPB) void k2_out(
    const float* __restrict__ W, const int* __restrict__ rel,
    const float* __restrict__ cbuf, const int* __restrict__ perm,
    const int* __restrict__ ntiles_p, float* __restrict__ out) {

    const int t = blockIdx.x;      // tile id
    if (t >= *ntiles_p) return;    // block-uniform

    const int tid  = threadIdx.x;
    const int wid  = tid >> 6;
    const int lane = tid & 63;

    __shared__ float Wl[32 * DD];  // 8 KB chunk: W_r[fc*32 .. +32][:]
    __shared__ int   e_sh[8], r_sh;

    if (tid < 8) e_sh[tid] = perm[t * 8 + tid];
    __syncthreads();
    if (tid == 0) {
        int rr = 0;
        #pragma unroll
        for (int i = 7; i >= 0; --i) if (e_sh[i] >= 0) rr = rel[e_sh[i]];
        r_sh = rr;
    }
    __syncthreads();

    const int e = e_sh[wid];
    const float* __restrict__ Wr = W + (size_t)r_sh * FF * DD;
    const float* __restrict__ ce = (e >= 0) ? (cbuf + (size_t)e * FF) : cbuf;

    const int fg = lane >> 4;      // 0..3: f within a 4-group
    const int dq = lane & 15;      // 0..15: d-quad
    const int srow = tid >> 4;     // 0..31: staging row
    const int scol = tid & 15;     // 0..15: staging float4 col

    float4 acc = make_float4(0.f, 0.f, 0.f, 0.f);
    #pragma unroll
    for (int fc = 0; fc < FF / 32; ++fc) {   // 8 chunks of 32 features
        // cooperative stage: 512 threads x 1 float4 = 8 KB, fully coalesced
        *(float4*)&Wl[srow * DD + scol * 4] =
            *(const float4*)&Wr[(size_t)(fc * 32 + srow) * DD + scol * 4];
        __syncthreads();
        if (e >= 0) {
            #pragma unroll
            for (int j = 0; j < 8; ++j) {
                int lf = j * 4 + fg;                    // local f 0..31
                float c = ce[fc * 32 + lf];             // L1-hot, 1KB/edge
                float4 w4 = *(const float4*)&Wl[lf * DD + dq * 4];
                acc.x = fmaf(c, w4.x, acc.x);
                acc.y = fmaf(c, w4.y, acc.y);
                acc.z = fmaf(c, w4.z, acc.z);
                acc.w = fmaf(c, w4.w, acc.w);
            }
        }
        __syncthreads();
    }

    // sum the 4 f-groups: lanes (l, l^16, l^32, l^48) hold same d-quad
    #pragma unroll
    for (int o = 16; o <= 32; o <<= 1) {
        acc.x += __shfl_xor(acc.x, o);
        acc.y += __shfl_xor(acc.y, o);
        acc.z += __shfl_xor(acc.z, o);
        acc.w += __shfl_xor(acc.w, o);
    }
    if (e >= 0 && fg == 0)
        *(float4*)&out[(size_t)e * DD + dq * 4] = acc;
}

extern "C" void kernel_launch(void* const* d_in, const int* in_sizes, int n_in,
                              void* d_out, int out_size, void* d_ws, size_t ws_size,
                              hipStream_t stream) {
    const float* x  = (const float*)d_in[0];   // [N, F]
    const float* W  = (const float*)d_in[1];   // [R, F, D]
    const float* a  = (const float*)d_in[2];   // [2*D]
    const int* src  = (const int*)d_in[3];     // [E]
    const int* dst  = (const int*)d_in[4];     // [E]
    const int* rel  = (const int*)d_in[5];     // [E]
    float* out      = (float*)d_out;           // [E*D]

    char* wsb = (char*)d_ws;
    int*   ntiles_p = (int*)wsb;
    int*   perm     = (int*)(wsb + 256);
    float* cbuf     = (float*)(wsb + 16384);

    k1_coef<<<FF, TPB, 0, stream>>>(x, W, a, src, dst, rel,
                                    cbuf, perm, ntiles_p);
    k2_out<<<K2_GRID, TPB, 0, stream>>>(W, rel, cbuf, perm, ntiles_p, out);
}